// Round 1
// baseline (3832.187 us; speedup 1.0000x reference)
//
#include <hip/hip_runtime.h>

#define Bsz 16384
#define TT 10
#define FF 500
#define H1c 256
#define H2c 100

__device__ __forceinline__ float sigm(float x) { return 1.0f / (1.0f + __expf(-x)); }

// ---------------------------------------------------------------------------
// LSTM step: z = x_t @ Wx + h_prev @ Wh + b ; gates i,f,g,o ; h,c update
// grid (B/64, 4), block 256. Block computes rows [r0,r0+64) x gate-cols
// [c0,c0+64) for ALL 4 gates (z cols g*256 + c0 + cc).
// ---------------------------------------------------------------------------
__global__ __launch_bounds__(256)
void lstm_step(const float* __restrict__ noise,
               const float* __restrict__ Wx, const float* __restrict__ Wh,
               const float* __restrict__ bias,
               const float* __restrict__ h_prev, const float* __restrict__ c_prev,
               float* __restrict__ h_out, float* __restrict__ c_out,
               int t, int first)
{
    __shared__ float xs[16][68];    // transposed [k][row], padded
    __shared__ float ws[16][256];   // [k][g*64 + cc]

    const int tid = threadIdx.x;
    const int r0 = blockIdx.x * 64;
    const int c0 = blockIdx.y * 64;
    const int tx = tid & 15, ty = tid >> 4;

    float acc[4][16];
    #pragma unroll
    for (int g = 0; g < 4; ++g)
        #pragma unroll
        for (int e = 0; e < 16; ++e) acc[g][e] = 0.f;

    const int sr = tid >> 2;          // staging row 0..63
    const int sc4 = (tid & 3) * 4;    // staging k offset

    // ---- K-loop A: x_t @ Wx, K=500 ----
    const float* xrow = noise + (size_t)(r0 + sr) * (TT * FF) + (size_t)t * FF;
    for (int kt = 0; kt < FF; kt += 16) {
        {
            int k = kt + sc4;
            float4 v = make_float4(0.f, 0.f, 0.f, 0.f);
            if (k + 3 < FF) v = *(const float4*)(xrow + k);
            else {
                if (k + 0 < FF) v.x = xrow[k + 0];
                if (k + 1 < FF) v.y = xrow[k + 1];
                if (k + 2 < FF) v.z = xrow[k + 2];
                if (k + 3 < FF) v.w = xrow[k + 3];
            }
            xs[sc4 + 0][sr] = v.x; xs[sc4 + 1][sr] = v.y;
            xs[sc4 + 2][sr] = v.z; xs[sc4 + 3][sr] = v.w;
        }
        #pragma unroll
        for (int q = 0; q < 4; ++q) {
            int idx4 = tid + q * 256;
            int kk = idx4 >> 6;
            int col4 = idx4 & 63;
            int g = col4 >> 4, cc4 = col4 & 15;
            float4 w = make_float4(0.f, 0.f, 0.f, 0.f);
            if (kt + kk < FF)
                w = *(const float4*)(Wx + (size_t)(kt + kk) * 1024 + g * 256 + c0 + cc4 * 4);
            *(float4*)&ws[kk][col4 * 4] = w;
        }
        __syncthreads();
        #pragma unroll
        for (int k = 0; k < 16; ++k) {
            float4 a4 = *(const float4*)&xs[k][ty * 4];
            float av[4] = {a4.x, a4.y, a4.z, a4.w};
            #pragma unroll
            for (int g = 0; g < 4; ++g) {
                float4 b4 = *(const float4*)&ws[k][g * 64 + tx * 4];
                float bv[4] = {b4.x, b4.y, b4.z, b4.w};
                #pragma unroll
                for (int i = 0; i < 4; ++i)
                    #pragma unroll
                    for (int j = 0; j < 4; ++j)
                        acc[g][i * 4 + j] += av[i] * bv[j];
            }
        }
        __syncthreads();
    }

    // ---- K-loop B: h_prev @ Wh, K=256 (skip at t==0, h0=0) ----
    if (!first) {
        const float* hrow = h_prev + (size_t)(r0 + sr) * H1c;
        for (int kt = 0; kt < H1c; kt += 16) {
            {
                float4 v = *(const float4*)(hrow + kt + sc4);
                xs[sc4 + 0][sr] = v.x; xs[sc4 + 1][sr] = v.y;
                xs[sc4 + 2][sr] = v.z; xs[sc4 + 3][sr] = v.w;
            }
            #pragma unroll
            for (int q = 0; q < 4; ++q) {
                int idx4 = tid + q * 256;
                int kk = idx4 >> 6;
                int col4 = idx4 & 63;
                int g = col4 >> 4, cc4 = col4 & 15;
                float4 w = *(const float4*)(Wh + (size_t)(kt + kk) * 1024 + g * 256 + c0 + cc4 * 4);
                *(float4*)&ws[kk][col4 * 4] = w;
            }
            __syncthreads();
            #pragma unroll
            for (int k = 0; k < 16; ++k) {
                float4 a4 = *(const float4*)&xs[k][ty * 4];
                float av[4] = {a4.x, a4.y, a4.z, a4.w};
                #pragma unroll
                for (int g = 0; g < 4; ++g) {
                    float4 b4 = *(const float4*)&ws[k][g * 64 + tx * 4];
                    float bv[4] = {b4.x, b4.y, b4.z, b4.w};
                    #pragma unroll
                    for (int i = 0; i < 4; ++i)
                        #pragma unroll
                        for (int j = 0; j < 4; ++j)
                            acc[g][i * 4 + j] += av[i] * bv[j];
                }
            }
            __syncthreads();
        }
    }

    // ---- epilogue: gates + state update ----
    const int col = c0 + tx * 4;
    #pragma unroll
    for (int i = 0; i < 4; ++i) {
        const int row = r0 + ty * 4 + i;
        float cpv[4] = {0.f, 0.f, 0.f, 0.f};
        if (!first) {
            float4 cp4 = *(const float4*)(c_prev + (size_t)row * H1c + col);
            cpv[0] = cp4.x; cpv[1] = cp4.y; cpv[2] = cp4.z; cpv[3] = cp4.w;
        }
        float hn[4], cn[4];
        #pragma unroll
        for (int j = 0; j < 4; ++j) {
            float zi = acc[0][i * 4 + j] + bias[0 * 256 + col + j];
            float zf = acc[1][i * 4 + j] + bias[1 * 256 + col + j];
            float zg = acc[2][i * 4 + j] + bias[2 * 256 + col + j];
            float zo = acc[3][i * 4 + j] + bias[3 * 256 + col + j];
            float ig = sigm(zi), fg = sigm(zf), og = sigm(zo);
            float gg = fmaxf(zg, 0.f);
            float cv = fg * cpv[j] + ig * gg;
            float hv = og * fmaxf(cv, 0.f);
            cn[j] = cv; hn[j] = hv;
        }
        *(float4*)(c_out + (size_t)row * H1c + col) = make_float4(cn[0], cn[1], cn[2], cn[3]);
        *(float4*)(h_out + (size_t)row * H1c + col) = make_float4(hn[0], hn[1], hn[2], hn[3]);
    }
}

// ---------------------------------------------------------------------------
// GRU step (Keras reset_after=True, activation=relu):
// mx = h_t @ Wxg + b_in ; mh = g_prev @ Whg + b_rec
// z=sig(mxz+mhz) r=sig(mxr+mhr) hc=relu(mxh + r*mhh) ; g = z*g + (1-z)*hc
// grid (B/64, 2), block 256. Gate-cols [c0,c0+64) (clipped at 100), 3 gates.
// ---------------------------------------------------------------------------
__global__ __launch_bounds__(256)
void gru_step(const float* __restrict__ hx,
              const float* __restrict__ Wxg, const float* __restrict__ Whg,
              const float* __restrict__ b_in, const float* __restrict__ b_rec,
              const float* __restrict__ g_prev, float* __restrict__ g_out,
              int first)
{
    __shared__ float xs[16][68];
    __shared__ float ws[16][192];   // [k][g*64 + cc]

    const int tid = threadIdx.x;
    const int r0 = blockIdx.x * 64;
    const int c0 = blockIdx.y * 64;
    const int tx = tid & 15, ty = tid >> 4;

    float accA[3][16], accB[3][16];
    #pragma unroll
    for (int g = 0; g < 3; ++g)
        #pragma unroll
        for (int e = 0; e < 16; ++e) { accA[g][e] = 0.f; accB[g][e] = 0.f; }

    const int sr = tid >> 2;
    const int sc4 = (tid & 3) * 4;

    // ---- K-loop A: h_t @ Wxg, K=256 ----
    const float* xrow = hx + (size_t)(r0 + sr) * H1c;
    for (int kt = 0; kt < H1c; kt += 16) {
        {
            float4 v = *(const float4*)(xrow + kt + sc4);
            xs[sc4 + 0][sr] = v.x; xs[sc4 + 1][sr] = v.y;
            xs[sc4 + 2][sr] = v.z; xs[sc4 + 3][sr] = v.w;
        }
        #pragma unroll
        for (int q = 0; q < 3; ++q) {
            int idx4 = tid + q * 256;            // 0..767
            int kk = idx4 / 48;                  // 0..15
            int col4 = idx4 % 48;                // 0..47
            int g = col4 >> 4, cc4 = col4 & 15;
            int gc = c0 + cc4 * 4;
            float4 w = make_float4(0.f, 0.f, 0.f, 0.f);
            if (gc < H2c)
                w = *(const float4*)(Wxg + (size_t)(kt + kk) * 300 + g * 100 + gc);
            *(float4*)&ws[kk][col4 * 4] = w;
        }
        __syncthreads();
        #pragma unroll
        for (int k = 0; k < 16; ++k) {
            float4 a4 = *(const float4*)&xs[k][ty * 4];
            float av[4] = {a4.x, a4.y, a4.z, a4.w};
            #pragma unroll
            for (int g = 0; g < 3; ++g) {
                float4 b4 = *(const float4*)&ws[k][g * 64 + tx * 4];
                float bv[4] = {b4.x, b4.y, b4.z, b4.w};
                #pragma unroll
                for (int i = 0; i < 4; ++i)
                    #pragma unroll
                    for (int j = 0; j < 4; ++j)
                        accA[g][i * 4 + j] += av[i] * bv[j];
            }
        }
        __syncthreads();
    }

    // ---- K-loop B: g_prev @ Whg, K=100 (skip at t==0) ----
    if (!first) {
        const float* grow = g_prev + (size_t)(r0 + sr) * H2c;
        for (int kt = 0; kt < H2c; kt += 16) {
            {
                int k = kt + sc4;
                float4 v = make_float4(0.f, 0.f, 0.f, 0.f);
                if (k < H2c) v = *(const float4*)(grow + k);   // k mult of 4, 100%4==0
                xs[sc4 + 0][sr] = v.x; xs[sc4 + 1][sr] = v.y;
                xs[sc4 + 2][sr] = v.z; xs[sc4 + 3][sr] = v.w;
            }
            #pragma unroll
            for (int q = 0; q < 3; ++q) {
                int idx4 = tid + q * 256;
                int kk = idx4 / 48;
                int col4 = idx4 % 48;
                int g = col4 >> 4, cc4 = col4 & 15;
                int gc = c0 + cc4 * 4;
                float4 w = make_float4(0.f, 0.f, 0.f, 0.f);
                if ((kt + kk) < H2c && gc < H2c)
                    w = *(const float4*)(Whg + (size_t)(kt + kk) * 300 + g * 100 + gc);
                *(float4*)&ws[kk][col4 * 4] = w;
            }
            __syncthreads();
            #pragma unroll
            for (int k = 0; k < 16; ++k) {
                float4 a4 = *(const float4*)&xs[k][ty * 4];
                float av[4] = {a4.x, a4.y, a4.z, a4.w};
                #pragma unroll
                for (int g = 0; g < 3; ++g) {
                    float4 b4 = *(const float4*)&ws[k][g * 64 + tx * 4];
                    float bv[4] = {b4.x, b4.y, b4.z, b4.w};
                    #pragma unroll
                    for (int i = 0; i < 4; ++i)
                        #pragma unroll
                        for (int j = 0; j < 4; ++j)
                            accB[g][i * 4 + j] += av[i] * bv[j];
                }
            }
            __syncthreads();
        }
    }

    // ---- epilogue ----
    const int col = c0 + tx * 4;
    if (col < H2c) {   // 100%4==0 -> whole float4 valid
        #pragma unroll
        for (int i = 0; i < 4; ++i) {
            const int row = r0 + ty * 4 + i;
            float gpv[4] = {0.f, 0.f, 0.f, 0.f};
            if (!first) {
                float4 g4 = *(const float4*)(g_prev + (size_t)row * H2c + col);
                gpv[0] = g4.x; gpv[1] = g4.y; gpv[2] = g4.z; gpv[3] = g4.w;
            }
            float gn[4];
            #pragma unroll
            for (int j = 0; j < 4; ++j) {
                float mxz = accA[0][i * 4 + j] + b_in[0 * 100 + col + j];
                float mxr = accA[1][i * 4 + j] + b_in[1 * 100 + col + j];
                float mxh = accA[2][i * 4 + j] + b_in[2 * 100 + col + j];
                float mhz = accB[0][i * 4 + j] + b_rec[0 * 100 + col + j];
                float mhr = accB[1][i * 4 + j] + b_rec[1 * 100 + col + j];
                float mhh = accB[2][i * 4 + j] + b_rec[2 * 100 + col + j];
                float zz = sigm(mxz + mhz);
                float rr = sigm(mxr + mhr);
                float hc = fmaxf(mxh + rr * mhh, 0.f);
                gn[j] = zz * gpv[j] + (1.f - zz) * hc;
            }
            *(float4*)(g_out + (size_t)row * H2c + col) = make_float4(gn[0], gn[1], gn[2], gn[3]);
        }
    }
}

// ---------------------------------------------------------------------------
// Dense: out = relu(g @ Wd + bd), [B,100]@[100,10]
// ---------------------------------------------------------------------------
__global__ __launch_bounds__(256)
void dense_out(const float* __restrict__ hg, const float* __restrict__ Wd,
               const float* __restrict__ bd, float* __restrict__ out)
{
    __shared__ float wd_s[H2c * TT];
    __shared__ float bd_s[TT];
    const int tid = threadIdx.x;
    for (int i = tid; i < H2c * TT; i += 256) wd_s[i] = Wd[i];
    if (tid < TT) bd_s[tid] = bd[tid];
    __syncthreads();

    const int row = blockIdx.x * 256 + tid;
    float acc[TT];
    #pragma unroll
    for (int j = 0; j < TT; ++j) acc[j] = 0.f;
    const float* hrow = hg + (size_t)row * H2c;
    for (int k = 0; k < H2c; ++k) {
        float xv = hrow[k];
        #pragma unroll
        for (int j = 0; j < TT; ++j) acc[j] += xv * wd_s[k * TT + j];
    }
    #pragma unroll
    for (int j = 0; j < TT; ++j)
        out[(size_t)row * TT + j] = fmaxf(acc[j] + bd_s[j], 0.f);
}

// ---------------------------------------------------------------------------
extern "C" void kernel_launch(void* const* d_in, const int* in_sizes, int n_in,
                              void* d_out, int out_size, void* d_ws, size_t ws_size,
                              hipStream_t stream)
{
    const float* noise  = (const float*)d_in[0];
    const float* Wx_l   = (const float*)d_in[1];
    const float* Wh_l   = (const float*)d_in[2];
    const float* b_l    = (const float*)d_in[3];
    const float* Wx_g   = (const float*)d_in[4];
    const float* Wh_g   = (const float*)d_in[5];
    const float* b_in   = (const float*)d_in[6];
    const float* b_rec  = (const float*)d_in[7];
    const float* Wd     = (const float*)d_in[8];
    const float* bd     = (const float*)d_in[9];
    float* outf = (float*)d_out;

    float* wsf = (float*)d_ws;
    const size_t NH = (size_t)Bsz * H1c;
    const size_t NG = (size_t)Bsz * H2c;
    float* hA = wsf;
    float* hB = hA + NH;
    float* cA = hB + NH;
    float* cB = cA + NH;
    float* gA = cB + NH;
    float* gB = gA + NG;

    float* h_r = hB; float* c_r = cB; float* g_r = gB;
    float* h_w = hA; float* c_w = cA; float* g_w = gA;
    float* g_last = gA;

    for (int t = 0; t < TT; ++t) {
        lstm_step<<<dim3(Bsz / 64, 4), 256, 0, stream>>>(
            noise, Wx_l, Wh_l, b_l, h_r, c_r, h_w, c_w, t, t == 0 ? 1 : 0);
        gru_step<<<dim3(Bsz / 64, 2), 256, 0, stream>>>(
            h_w, Wx_g, Wh_g, b_in, b_rec, g_r, g_w, t == 0 ? 1 : 0);
        g_last = g_w;
        float* tmp;
        tmp = h_r; h_r = h_w; h_w = tmp;
        tmp = c_r; c_r = c_w; c_w = tmp;
        tmp = g_r; g_r = g_w; g_w = tmp;
    }
    dense_out<<<Bsz / 256, 256, 0, stream>>>(g_last, Wd, bd, outf);
}

// Round 2
// 931.746 us; speedup vs baseline: 4.1129x; 4.1129x over previous
//
#include <hip/hip_runtime.h>

#define Bsz 16384
#define TT 10
#define FF 500
#define H1c 256
#define H2c 100

typedef _Float16 half8 __attribute__((ext_vector_type(8)));
typedef float floatx4 __attribute__((ext_vector_type(4)));

__device__ __forceinline__ float sigm(float x) { return 1.0f / (1.0f + __expf(-x)); }

#define GLOAD16(g, l) __builtin_amdgcn_global_load_lds( \
    (const __attribute__((address_space(1))) void*)(g), \
    (__attribute__((address_space(3))) void*)(l), 16, 0, 0)

// ---------------------------------------------------------------------------
// x slice convert: noise[b][t*500 + k] fp32 -> xc[b][512] fp16 (zero-padded)
// ---------------------------------------------------------------------------
__global__ __launch_bounds__(256)
void conv_x(const float* __restrict__ noise, _Float16* __restrict__ xc, int t)
{
    const int idx = blockIdx.x * 256 + threadIdx.x;   // Bsz*64 threads
    const int b = idx >> 6;
    const int kc = (idx & 63) << 3;
    const float* src = noise + (size_t)b * (TT * FF) + t * FF + kc;
    half8 v;
    if (kc + 8 <= FF) {
        float4 u0 = *(const float4*)src;
        float4 u1 = *(const float4*)(src + 4);
        v[0] = (_Float16)u0.x; v[1] = (_Float16)u0.y; v[2] = (_Float16)u0.z; v[3] = (_Float16)u0.w;
        v[4] = (_Float16)u1.x; v[5] = (_Float16)u1.y; v[6] = (_Float16)u1.z; v[7] = (_Float16)u1.w;
    } else {
        #pragma unroll
        for (int j = 0; j < 8; ++j)
            v[j] = (kc + j < FF) ? (_Float16)src[j] : (_Float16)0.f;
    }
    *(half8*)(xc + (size_t)b * 512 + kc) = v;
}

// ---------------------------------------------------------------------------
// LSTM weight prep: WT[n'][k], n' = 128*(U>>5) + 64*((U>>4)&1) + 16*g + (U&15)
// k in [0,512): Wx rows (500 real, pad 0); k in [512,768): Wh rows.
// ---------------------------------------------------------------------------
__global__ __launch_bounds__(256)
void prep_lstm_w(const float* __restrict__ Wx, const float* __restrict__ Wh,
                 _Float16* __restrict__ WT)
{
    const int idx = blockIdx.x * 256 + threadIdx.x;   // 1024*768
    const int np = idx / 768, k = idx % 768;
    const int a = np >> 7, b2 = (np >> 6) & 1, g = (np >> 4) & 3, u = np & 15;
    const int U = a * 32 + b2 * 16 + u;
    const int col = g * 256 + U;
    float v = 0.f;
    if (k < 512) { if (k < FF) v = Wx[(size_t)k * 1024 + col]; }
    else v = Wh[(size_t)(k - 512) * 1024 + col];
    WT[idx] = (_Float16)v;
}

// ---------------------------------------------------------------------------
// GRU weight prep: WT[n'][k], n' = 96*(U>>5) + 48*((U>>4)&1) + 16*g + (U&15),
// U in [0,128) (units padded 100->128). k<256: Wxg rows; k in [256,384): Whg.
// ---------------------------------------------------------------------------
__global__ __launch_bounds__(256)
void prep_gru_w(const float* __restrict__ Wxg, const float* __restrict__ Whg,
                _Float16* __restrict__ WT)
{
    const int idx = blockIdx.x * 256 + threadIdx.x;   // 384*384
    if (idx >= 384 * 384) return;
    const int np = idx / 384, k = idx % 384;
    const int nb = np / 96, rem = np % 96;
    const int wxx = rem / 48, g = (rem % 48) / 16, u = rem & 15;
    const int U = nb * 32 + wxx * 16 + u;
    float v = 0.f;
    if (U < H2c) {
        if (k < 256) v = Wxg[(size_t)k * 300 + g * H2c + U];
        else if (k - 256 < H2c) v = Whg[(size_t)(k - 256) * 300 + g * H2c + U];
    }
    WT[idx] = (_Float16)v;
}

// ---------------------------------------------------------------------------
// LSTM step via MFMA. C[16384,1024] = [xc | h_prev] @ WT^T, fused gate epilogue.
// Block 128x128, 4 waves 2x2, BK=32. grid (128, 8).
// ---------------------------------------------------------------------------
__global__ __launch_bounds__(256)
void lstm_mfma(const _Float16* __restrict__ xc, const _Float16* __restrict__ WT,
               const float* __restrict__ bias,
               const _Float16* __restrict__ h_prev, const float* __restrict__ c_prev,
               _Float16* __restrict__ h_out, float* __restrict__ c_out, int first)
{
    __shared__ _Float16 As[128 * 32];
    __shared__ _Float16 Bs[128 * 32];

    const int tid = threadIdx.x;
    const int lane = tid & 63;
    const int w = tid >> 6;
    const int wy = w >> 1, wx = w & 1;
    const int row0 = blockIdx.x * 128;
    const int nb = blockIdx.y;

    floatx4 acc[4][4];
    #pragma unroll
    for (int a = 0; a < 4; ++a)
        #pragma unroll
        for (int b = 0; b < 4; ++b) acc[a][b] = (floatx4){0.f, 0.f, 0.f, 0.f};

    const int slr = lane >> 2;          // staging row within 16-row issue
    const int slc = (lane & 3) * 8;     // staging k offset (halves)
    const int fr = lane & 15;           // fragment row/col
    const int fk = (lane >> 4) * 8;     // fragment k offset

    const int nkt = first ? 16 : 24;
    for (int kt8 = 0; kt8 < nkt; ++kt8) {
        const int kb = kt8 * 32;
        #pragma unroll
        for (int i = 0; i < 2; ++i) {
            const int r = w * 32 + i * 16;
            GLOAD16(WT + (size_t)(nb * 128 + r + slr) * 768 + kb + slc, &Bs[r * 32]);
        }
        if (kt8 < 16) {
            #pragma unroll
            for (int i = 0; i < 2; ++i) {
                const int r = w * 32 + i * 16;
                GLOAD16(xc + (size_t)(row0 + r + slr) * 512 + kb + slc, &As[r * 32]);
            }
        } else {
            #pragma unroll
            for (int i = 0; i < 2; ++i) {
                const int r = w * 32 + i * 16;
                GLOAD16(h_prev + (size_t)(row0 + r + slr) * 256 + (kb - 512) + slc, &As[r * 32]);
            }
        }
        __syncthreads();
        half8 af[4], bf[4];
        #pragma unroll
        for (int mi = 0; mi < 4; ++mi)
            af[mi] = *(const half8*)&As[(wy * 64 + mi * 16 + fr) * 32 + fk];
        #pragma unroll
        for (int ni = 0; ni < 4; ++ni)
            bf[ni] = *(const half8*)&Bs[(wx * 64 + ni * 16 + fr) * 32 + fk];
        #pragma unroll
        for (int mi = 0; mi < 4; ++mi)
            #pragma unroll
            for (int ni = 0; ni < 4; ++ni)
                acc[mi][ni] = __builtin_amdgcn_mfma_f32_16x16x32_f16(af[mi], bf[ni], acc[mi][ni], 0, 0, 0);
        __syncthreads();
    }

    // epilogue: lane owns unit U, gates = ni fragments
    const int U = nb * 32 + wx * 16 + fr;
    const float bi = bias[0 * 256 + U];
    const float bff = bias[1 * 256 + U];
    const float bg = bias[2 * 256 + U];
    const float bo = bias[3 * 256 + U];
    const int rbase = row0 + wy * 64 + (lane >> 4) * 4;
    #pragma unroll
    for (int mi = 0; mi < 4; ++mi) {
        #pragma unroll
        for (int r = 0; r < 4; ++r) {
            const int row = rbase + mi * 16 + r;
            const float cp = first ? 0.f : c_prev[(size_t)row * 256 + U];
            const float zi = acc[mi][0][r] + bi;
            const float zf = acc[mi][1][r] + bff;
            const float zg = acc[mi][2][r] + bg;
            const float zo = acc[mi][3][r] + bo;
            const float ig = sigm(zi), fg = sigm(zf), og = sigm(zo);
            const float gg = fmaxf(zg, 0.f);
            const float cv = fg * cp + ig * gg;
            const float hv = og * fmaxf(cv, 0.f);
            c_out[(size_t)row * 256 + U] = cv;
            h_out[(size_t)row * 256 + U] = (_Float16)hv;
        }
    }
}

// ---------------------------------------------------------------------------
// GRU step via MFMA. mx = h @ Wxg (K=256), mh = g_prev @ Whg (K=128 padded).
// Block 128x96 (3 gates x 32 units), 4 waves 2x2 (wave tile 64x48). grid (128,4).
// ---------------------------------------------------------------------------
__global__ __launch_bounds__(256)
void gru_mfma(const _Float16* __restrict__ hx, const _Float16* __restrict__ WT,
              const float* __restrict__ b_in, const float* __restrict__ b_rec,
              const float* __restrict__ g_prev, const _Float16* __restrict__ g16_prev,
              float* __restrict__ g_out, _Float16* __restrict__ g16_out, int first)
{
    __shared__ _Float16 As[128 * 32];
    __shared__ _Float16 Bs[96 * 32];

    const int tid = threadIdx.x;
    const int lane = tid & 63;
    const int w = tid >> 6;
    const int wy = w >> 1, wx = w & 1;
    const int row0 = blockIdx.x * 128;
    const int nb = blockIdx.y;

    floatx4 accA[4][3], accB[4][3];
    #pragma unroll
    for (int a = 0; a < 4; ++a)
        #pragma unroll
        for (int b = 0; b < 3; ++b) {
            accA[a][b] = (floatx4){0.f, 0.f, 0.f, 0.f};
            accB[a][b] = (floatx4){0.f, 0.f, 0.f, 0.f};
        }

    const int slr = lane >> 2;
    const int slc = (lane & 3) * 8;
    const int fr = lane & 15;
    const int fk = (lane >> 4) * 8;

    const int nkt = first ? 8 : 12;
    for (int kt8 = 0; kt8 < nkt; ++kt8) {
        const int kb = kt8 * 32;
        for (int i = w; i < 6; i += 4)
            GLOAD16(WT + (size_t)(nb * 96 + i * 16 + slr) * 384 + kb + slc, &Bs[i * 16 * 32]);
        if (kt8 < 8) {
            #pragma unroll
            for (int i = 0; i < 2; ++i) {
                const int r = w * 32 + i * 16;
                GLOAD16(hx + (size_t)(row0 + r + slr) * 256 + kb + slc, &As[r * 32]);
            }
        } else {
            #pragma unroll
            for (int i = 0; i < 2; ++i) {
                const int r = w * 32 + i * 16;
                GLOAD16(g16_prev + (size_t)(row0 + r + slr) * 128 + (kb - 256) + slc, &As[r * 32]);
            }
        }
        __syncthreads();
        half8 af[4], bf[3];
        #pragma unroll
        for (int mi = 0; mi < 4; ++mi)
            af[mi] = *(const half8*)&As[(wy * 64 + mi * 16 + fr) * 32 + fk];
        #pragma unroll
        for (int ni = 0; ni < 3; ++ni)
            bf[ni] = *(const half8*)&Bs[(wx * 48 + ni * 16 + fr) * 32 + fk];
        if (kt8 < 8) {
            #pragma unroll
            for (int mi = 0; mi < 4; ++mi)
                #pragma unroll
                for (int ni = 0; ni < 3; ++ni)
                    accA[mi][ni] = __builtin_amdgcn_mfma_f32_16x16x32_f16(af[mi], bf[ni], accA[mi][ni], 0, 0, 0);
        } else {
            #pragma unroll
            for (int mi = 0; mi < 4; ++mi)
                #pragma unroll
                for (int ni = 0; ni < 3; ++ni)
                    accB[mi][ni] = __builtin_amdgcn_mfma_f32_16x16x32_f16(af[mi], bf[ni], accB[mi][ni], 0, 0, 0);
        }
        __syncthreads();
    }

    const int U = nb * 32 + wx * 16 + fr;
    const bool uv = U < H2c;
    const float bzi = uv ? b_in[U] : 0.f;
    const float bri = uv ? b_in[H2c + U] : 0.f;
    const float bhi = uv ? b_in[2 * H2c + U] : 0.f;
    const float bzr = uv ? b_rec[U] : 0.f;
    const float brr = uv ? b_rec[H2c + U] : 0.f;
    const float bhr = uv ? b_rec[2 * H2c + U] : 0.f;
    const int rbase = row0 + wy * 64 + (lane >> 4) * 4;
    #pragma unroll
    for (int mi = 0; mi < 4; ++mi) {
        #pragma unroll
        for (int r = 0; r < 4; ++r) {
            const int row = rbase + mi * 16 + r;
            const float gp = (!first && uv) ? g_prev[(size_t)row * H2c + U] : 0.f;
            const float mxz = accA[mi][0][r] + bzi;
            const float mxr = accA[mi][1][r] + bri;
            const float mxh = accA[mi][2][r] + bhi;
            const float mhz = accB[mi][0][r] + bzr;
            const float mhr = accB[mi][1][r] + brr;
            const float mhh = accB[mi][2][r] + bhr;
            const float z = sigm(mxz + mhz);
            const float rr = sigm(mxr + mhr);
            const float hc = fmaxf(mxh + rr * mhh, 0.f);
            const float g = z * gp + (1.f - z) * hc;
            if (uv) g_out[(size_t)row * H2c + U] = g;
            g16_out[(size_t)row * 128 + U] = uv ? (_Float16)g : (_Float16)0.f;
        }
    }
}

// ---------------------------------------------------------------------------
// Dense: out = relu(g @ Wd + bd), [B,100]@[100,10]
// ---------------------------------------------------------------------------
__global__ __launch_bounds__(256)
void dense_out(const float* __restrict__ hg, const float* __restrict__ Wd,
               const float* __restrict__ bd, float* __restrict__ out)
{
    __shared__ float wd_s[H2c * TT];
    __shared__ float bd_s[TT];
    const int tid = threadIdx.x;
    for (int i = tid; i < H2c * TT; i += 256) wd_s[i] = Wd[i];
    if (tid < TT) bd_s[tid] = bd[tid];
    __syncthreads();

    const int row = blockIdx.x * 256 + tid;
    float acc[TT];
    #pragma unroll
    for (int j = 0; j < TT; ++j) acc[j] = 0.f;
    const float* hrow = hg + (size_t)row * H2c;
    for (int k = 0; k < H2c; ++k) {
        float xv = hrow[k];
        #pragma unroll
        for (int j = 0; j < TT; ++j) acc[j] += xv * wd_s[k * TT + j];
    }
    #pragma unroll
    for (int j = 0; j < TT; ++j)
        out[(size_t)row * TT + j] = fmaxf(acc[j] + bd_s[j], 0.f);
}

// ---------------------------------------------------------------------------
extern "C" void kernel_launch(void* const* d_in, const int* in_sizes, int n_in,
                              void* d_out, int out_size, void* d_ws, size_t ws_size,
                              hipStream_t stream)
{
    const float* noise  = (const float*)d_in[0];
    const float* Wx_l   = (const float*)d_in[1];
    const float* Wh_l   = (const float*)d_in[2];
    const float* b_l    = (const float*)d_in[3];
    const float* Wx_g   = (const float*)d_in[4];
    const float* Wh_g   = (const float*)d_in[5];
    const float* b_in   = (const float*)d_in[6];
    const float* b_rec  = (const float*)d_in[7];
    const float* Wd     = (const float*)d_in[8];
    const float* bd     = (const float*)d_in[9];
    float* outf = (float*)d_out;

    char* p = (char*)d_ws;
    auto alloc = [&](size_t bytes) {
        char* r = p;
        p += (bytes + 255) & ~(size_t)255;
        return r;
    };
    _Float16* WTl  = (_Float16*)alloc((size_t)1024 * 768 * 2);
    _Float16* WTg  = (_Float16*)alloc((size_t)384 * 384 * 2);
    _Float16* xc   = (_Float16*)alloc((size_t)Bsz * 512 * 2);
    _Float16* h16A = (_Float16*)alloc((size_t)Bsz * 256 * 2);
    _Float16* h16B = (_Float16*)alloc((size_t)Bsz * 256 * 2);
    float*    cA   = (float*)alloc((size_t)Bsz * 256 * 4);
    float*    cB   = (float*)alloc((size_t)Bsz * 256 * 4);
    float*    gA   = (float*)alloc((size_t)Bsz * 100 * 4);
    float*    gB   = (float*)alloc((size_t)Bsz * 100 * 4);
    _Float16* g16A = (_Float16*)alloc((size_t)Bsz * 128 * 2);
    _Float16* g16B = (_Float16*)alloc((size_t)Bsz * 128 * 2);

    prep_lstm_w<<<1024 * 768 / 256, 256, 0, stream>>>(Wx_l, Wh_l, WTl);
    prep_gru_w<<<(384 * 384 + 255) / 256, 256, 0, stream>>>(Wx_g, Wh_g, WTg);

    _Float16 *h_r = h16B, *h_w = h16A;
    float *c_r = cB, *c_w = cA;
    float *g_r = gB, *g_w = gA;
    _Float16 *g16_r = g16B, *g16_w = g16A;
    float* g_last = gA;

    for (int t = 0; t < TT; ++t) {
        conv_x<<<Bsz * 64 / 256, 256, 0, stream>>>(noise, xc, t);
        lstm_mfma<<<dim3(Bsz / 128, 8), 256, 0, stream>>>(
            xc, WTl, b_l, h_r, c_r, h_w, c_w, t == 0 ? 1 : 0);
        gru_mfma<<<dim3(Bsz / 128, 4), 256, 0, stream>>>(
            h_w, WTg, b_in, b_rec, g_r, g16_r, g_w, g16_w, t == 0 ? 1 : 0);
        g_last = g_w;
        _Float16* th;
        float* tf;
        th = h_r; h_r = h_w; h_w = th;
        tf = c_r; c_r = c_w; c_w = tf;
        tf = g_r; g_r = g_w; g_w = tf;
        th = g16_r; g16_r = g16_w; g16_w = th;
    }
    dense_out<<<Bsz / 256, 256, 0, stream>>>(g_last, Wd, bd, outf);
}